// Round 9
// baseline (577.054 us; speedup 1.0000x reference)
//
#include <hip/hip_runtime.h>
#include <math.h>

// Problem constants
#define kN 50000
#define kE 800000
#define kM 4
#define kH 4
#define kC 32
#define kIN 256
#define kD 128   // kH*kC

typedef __attribute__((ext_vector_type(8))) short bf16x8;
typedef __attribute__((ext_vector_type(4))) float f32x4;

__device__ __forceinline__ unsigned int f2bf_pack(float a, float b) {
    unsigned ua = __float_as_uint(a);
    ua += 0x7fffu + ((ua >> 16) & 1u);          // RNE
    unsigned ub = __float_as_uint(b);
    ub += 0x7fffu + ((ub >> 16) & 1u);
    return (ua >> 16) | (ub & 0xffff0000u);
}
__device__ __forceinline__ unsigned short f2bf(float x) {
    unsigned u = __float_as_uint(x);
    u += 0x7fffu + ((u >> 16) & 1u);
    return (unsigned short)(u >> 16);
}

// ---------------------------------------------------------------------------
// Bucket-major CSR: 98 buckets of 512 dsts per metapath, fixed capacity.
#define NBK 98
#define BCAP 10240
#define MW (NBK * BCAP)               // per-m region: 1,003,520 slots
#define PAB ((kE + 4095) / 4096)      // 196 edge chunks per metapath

// ---------------------------------------------------------------------------
// Wt16[col][k] = bf16(W[k][col])  (128 cols x 256 k)
__global__ void k_wcast(const float* __restrict__ W, unsigned short* __restrict__ Wt16) {
    const int col = blockIdx.x;        // 0..127
    const int k = threadIdx.x;         // 0..255
    Wt16[(size_t)col * kIN + k] = f2bf(W[(size_t)k * kD + col]);
}

// ---------------------------------------------------------------------------
// FUSED: blocks [0,GEMMB) = MFMA bf16 GEMM + in-block slr epilogue.
//   h16 is written HEAD-MAJOR [kH][kN][kC] and sl/sr HEAD-MAJOR [kH][kM][kN]
//   so k_agg's per-(dst,head) blocks see contiguous, line-disjoint slices
//   (per-XCD L2 residency). blocks [GEMMB, ...) = bucket phase A.
#define GEMMB ((kN + 127) / 128)          // 391
__global__ __launch_bounds__(256) void k_gemmbucket(const float* __restrict__ feats,
                                                    const unsigned short* __restrict__ Wt16,
                                                    const float* __restrict__ b,
                                                    const float* __restrict__ attn,
                                                    unsigned short* __restrict__ h16t,
                                                    float* __restrict__ slt,
                                                    float* __restrict__ srt,
                                                    const int* __restrict__ ei,
                                                    int* __restrict__ bcur,
                                                    unsigned int* __restrict__ pairs) {
    // union: staging fr16 (128x32 u16 = 8192 B) | hlds (64x130 u16 = 16640 B)
    __shared__ __align__(16) unsigned char smem[64 * 130 * 2];
    __shared__ int hist[NBK], h2[NBK], base_s[NBK];
    const int t = threadIdx.x;

    if (blockIdx.x >= GEMMB) {
        // ---- bucket phase A ----
        const int bi = blockIdx.x - GEMMB;
        const int m = bi / PAB;
        const int chunk = bi - m * PAB;
        const int e0 = chunk * 4096;
        for (int j = t; j < NBK; j += 256) { hist[j] = 0; h2[j] = 0; }
        __syncthreads();
        int src[16], dst[16];
#pragma unroll
        for (int i = 0; i < 16; i++) {
            const int e = e0 + i * 256 + t;
            const int eok = (e < kE) ? e : 0;
            src[i] = ei[(size_t)m * 2 * kE + eok];
            dst[i] = (e < kE) ? ei[(size_t)m * 2 * kE + kE + eok] : -1;
        }
#pragma unroll
        for (int i = 0; i < 16; i++)
            if (dst[i] >= 0) atomicAdd(&hist[dst[i] >> 9], 1);
        __syncthreads();
        for (int j = t; j < NBK; j += 256)
            base_s[j] = atomicAdd(&bcur[m * NBK + j], hist[j]);
        __syncthreads();
#pragma unroll
        for (int i = 0; i < 16; i++) {
            if (dst[i] >= 0) {
                const int bk = dst[i] >> 9;
                const int slot = base_s[bk] + atomicAdd(&h2[bk], 1);
                pairs[(size_t)m * MW + (size_t)bk * BCAP + slot] =
                    ((unsigned int)(dst[i] & 511) << 16) | (unsigned int)src[i];
            }
        }
        return;
    }

    // ---- MFMA GEMM ----
    unsigned short* fr16 = reinterpret_cast<unsigned short*>(smem);
    typedef unsigned short hrow_t[130];
    hrow_t* hlds = reinterpret_cast<hrow_t*>(smem);

    const int lane = t & 63;
    const int wave = t >> 6;
    const int q = lane >> 4;           // quad 0..3
    const int m16 = lane & 15;
    const int wrow = (wave >> 1) * 64;
    const int wcol = (wave & 1) * 64;
    const int rowbase = blockIdx.x * 128;

    f32x4 acc[4][4];
#pragma unroll
    for (int i = 0; i < 4; i++)
#pragma unroll
        for (int j = 0; j < 4; j++) acc[i][j] = (f32x4){0.f, 0.f, 0.f, 0.f};

    const int srow = t >> 3;           // staging: 32 rows per pass
    const int sk4 = t & 7;             // float4 slot along k (8 slots = 32 k)

    for (int kc = 0; kc < kIN; kc += 32) {
        __syncthreads();
#pragma unroll
        for (int it = 0; it < 4; it++) {
            const int row = srow + it * 32;
            const int rg = rowbase + row;
            float4 v = make_float4(0.f, 0.f, 0.f, 0.f);
            if (rg < kN)
                v = *reinterpret_cast<const float4*>(feats + (size_t)rg * kIN + kc + sk4 * 4);
            uint2 p;
            p.x = f2bf_pack(v.x, v.y);
            p.y = f2bf_pack(v.z, v.w);
            *reinterpret_cast<uint2*>(&fr16[row * 32 + sk4 * 4]) = p;
        }
        __syncthreads();

        bf16x8 afr[4], bfr[4];
#pragma unroll
        for (int ri = 0; ri < 4; ri++)
            afr[ri] = *reinterpret_cast<const bf16x8*>(
                &fr16[(wrow + ri * 16 + m16) * 32 + q * 8]);
#pragma unroll
        for (int ci = 0; ci < 4; ci++)
            bfr[ci] = *reinterpret_cast<const bf16x8*>(
                Wt16 + (size_t)(wcol + ci * 16 + m16) * kIN + kc + q * 8);
#pragma unroll
        for (int ri = 0; ri < 4; ri++)
#pragma unroll
            for (int ci = 0; ci < 4; ci++)
                acc[ri][ci] = __builtin_amdgcn_mfma_f32_16x16x32_bf16(
                    afr[ri], bfr[ci], acc[ri][ci], 0, 0, 0);
    }

    float bcol[4];
#pragma unroll
    for (int ci = 0; ci < 4; ci++) bcol[ci] = b[wcol + ci * 16 + m16];

    // h16 global write, head-major [kH][kN][kC]
#pragma unroll
    for (int ri = 0; ri < 4; ri++) {
#pragma unroll
        for (int reg = 0; reg < 4; reg++) {
            const int row = wrow + ri * 16 + q * 4 + reg;
            const int rg = rowbase + row;
            if (rg < kN) {
#pragma unroll
                for (int ci = 0; ci < 4; ci++) {
                    const int col = wcol + ci * 16 + m16;
                    const int hd = col >> 5, ch = col & 31;
                    const float v = fmaxf(acc[ri][ci][reg] + bcol[ci], 0.f);
                    h16t[((size_t)hd * kN + rg) * kC + ch] = f2bf(v);
                }
            }
        }
    }
    __syncthreads();   // fr16 (last ds_reads) -> hlds aliasing hazard

    // ---- slr epilogue: two 64-row passes over the union'd LDS buffer ----
    const unsigned int* hl32 = reinterpret_cast<const unsigned int*>(smem);
#pragma unroll
    for (int half = 0; half < 2; half++) {
        if ((wrow >> 6) == half) {      // wave-uniform: waves owning these rows
#pragma unroll
            for (int ri = 0; ri < 4; ri++)
#pragma unroll
                for (int reg = 0; reg < 4; reg++) {
                    const int row = (wrow & 63) + ri * 16 + q * 4 + reg;
#pragma unroll
                    for (int ci = 0; ci < 4; ci++) {
                        const int col = wcol + ci * 16 + m16;
                        const float v = fmaxf(acc[ri][ci][reg] + bcol[ci], 0.f);
                        hlds[row][col] = f2bf(v);   // pad rows defined (zero feats)
                    }
                }
        }
        __syncthreads();
        {
            // wave w handles head w; lane = node; head-major sl/sr writes are
            // coalesced 64-float runs; LDS stride 65 words -> conflict-free.
            const int hh = t >> 6;
            const int nl = t & 63;             // 0..63
            const int n = rowbase + half * 64 + nl;
            if (n < kN) {
                unsigned int u[16];
#pragma unroll
                for (int k = 0; k < 16; k++) u[k] = hl32[nl * 65 + hh * 16 + k];
                float f0[16], f1[16];
#pragma unroll
                for (int k = 0; k < 16; k++) {
                    f0[k] = __uint_as_float(u[k] << 16);
                    f1[k] = __uint_as_float(u[k] & 0xffff0000u);
                }
#pragma unroll
                for (int m = 0; m < kM; m++) {
                    const float2* al = reinterpret_cast<const float2*>(attn + (m * kH + hh) * 2 * kC);
                    const float2* ar = al + 16;
                    float s0 = 0.f, s1 = 0.f;
#pragma unroll
                    for (int k = 0; k < 16; k++) {
                        const float2 a = al[k], r = ar[k];
                        s0 += f0[k] * a.x + f1[k] * a.y;
                        s1 += f0[k] * r.x + f1[k] * r.y;
                    }
                    slt[((size_t)hh * kM + m) * kN + n] = s0;   // head-major
                    srt[((size_t)hh * kM + m) * kN + n] = s1;
                }
            }
        }
        __syncthreads();
    }
}

// ---------------------------------------------------------------------------
// Per-(m,bucket) LOCAL count+scan+place, single pass over pairs (unchanged).
#define SORTB (kM * NBK)                       // 392
__global__ __launch_bounds__(256) void k_sort(const unsigned int* __restrict__ pairs,
                                              const int* __restrict__ bcur,
                                              int* __restrict__ offs,
                                              int* __restrict__ cnta,
                                              unsigned short* __restrict__ srcsort) {
    __shared__ int hist[512], pref[512], h2[512], wt[4];
    const int t = threadIdx.x;
    const int m = blockIdx.x / NBK;
    const int bk = blockIdx.x - m * NBK;
    const int bs = bk << 9;
    const int base = bk * BCAP;
    const int n = bcur[m * NBK + bk];          // exact bucket fill from phase A
    const unsigned int* __restrict__ pb = pairs + (size_t)m * MW + base;
    unsigned short* __restrict__ ss = srcsort + (size_t)m * MW + base;

    hist[t] = 0; hist[t + 256] = 0; h2[t] = 0; h2[t + 256] = 0;
    __syncthreads();

    unsigned int v[40];
#pragma unroll
    for (int j = 0; j < 40; j++) {
        const int idx = j * 256 + t;
        v[j] = (idx < n) ? pb[idx] : 0xffffffffu;   // valid pairs < 0x02000000
    }
#pragma unroll
    for (int j = 0; j < 40; j++)
        if (v[j] != 0xffffffffu) atomicAdd(&hist[v[j] >> 16], 1);
    __syncthreads();

    const int lane = t & 63, wid = t >> 6;
    const int j0 = 2 * t, j1 = 2 * t + 1;
    const int h0 = hist[j0], h1 = hist[j1];
    const int s = h0 + h1;
    int incl = s;
#pragma unroll
    for (int d = 1; d < 64; d <<= 1) {
        const int x = __shfl_up(incl, d);
        if (lane >= d) incl += x;
    }
    if (lane == 63) wt[wid] = incl;
    __syncthreads();
    int woff = 0;
#pragma unroll
    for (int i = 0; i < 4; i++)
        if (i < wid) woff += wt[i];
    const int excl = woff + incl - s;
    pref[j0] = excl;
    pref[j1] = excl + h0;
    const int d0 = bs + j0, d1 = bs + j1;
    if (d0 < kN) { offs[m * kN + d0] = base + excl;       cnta[m * kN + d0] = h0; }
    if (d1 < kN) { offs[m * kN + d1] = base + excl + h0;  cnta[m * kN + d1] = h1; }
    __syncthreads();

#pragma unroll
    for (int j = 0; j < 40; j++) {
        if (v[j] != 0xffffffffu) {
            const int dl = (int)(v[j] >> 16);
            const int pos = pref[dl] + atomicAdd(&h2[dl], 1);
            ss[pos] = (unsigned short)(v[j] & 0xffffu);
        }
    }
    // zero the over-read slack (reads never exceed n+48; stay inside window)
    if (t < 64 && n + t < BCAP) ss[n + t] = 0;
}

// ---------------------------------------------------------------------------
// aggregation R15: HEAD-SLICED, XCD-pinned. Block = (dst, head) via
// blockIdx%8 -> XCD round-robin: head = xcd>>1, so each XCD touches only its
// head's h16t slice (50000 x 64 B = 3.2 MB < 4 MiB L2) + srt slice (0.8 MB)
// -> h16 gathers become L2 hits instead of 65% capacity misses. Relation
// softmax is head-local (beta[n,r,h]) so the block is self-contained.
// Streams (srcsort/offs/cnta/sl/out) use nontemporal hints to protect the
// resident set. Weight math recomputed per head-block (same total exp count
// as before: weights were always per (edge,head)).
#define CH2 16
__global__ __launch_bounds__(256) void k_agg(const unsigned short* __restrict__ h16t,
                                             const float* __restrict__ slt,
                                             const float* __restrict__ srt,
                                             const int* __restrict__ offs,
                                             const int* __restrict__ cnta,
                                             const unsigned short* __restrict__ srcsort,
                                             const float* __restrict__ ral,
                                             const float* __restrict__ rar,
                                             const float* __restrict__ rbias,
                                             float* __restrict__ out) {
    const int i = blockIdx.x;
    const int xcd = i & 7;
    const int hh = xcd >> 1;                    // head pinned to an XCD pair
    const int dst = ((i >> 3) << 1) | (xcd & 1);
    const int t = threadIdx.x;
    const int m = t >> 6;
    const int l = t & 63;
    const int cp = l & 15;                      // channel pair (2 ch of 32)
    const int eg = l >> 4;                      // edge group 0..3

    __shared__ float smres[kM][16][2];

    const int beg = __builtin_nontemporal_load(&offs[m * kN + dst]);
    const int cnt = __builtin_nontemporal_load(&cnta[m * kN + dst]);
    const float sl_h = __builtin_nontemporal_load(&slt[((size_t)hh * kM + m) * kN + dst]);
    const unsigned short* __restrict__ sbase = srcsort + (size_t)m * MW + beg;
    const char* __restrict__ hb = (const char*)(h16t + (size_t)hh * kN * kC);
    const float* __restrict__ srb = srt + ((size_t)hh * kM + m) * kN;
    const unsigned int cbyte = (unsigned int)(cp << 2);

    float sum = 0.f, a0 = 0.f, a1 = 0.f;

    for (int c = 0; c < cnt; c += CH2) {
        // lane cp loads edge (c+cp)'s id; over-read lands in zeroed slack or
        // the next dst's valid ids (weight forced 0, gather clamped below)
        const int idv = (int)__builtin_nontemporal_load(&sbase[c + cp]);
        const float srv = srb[idv];             // cached: 0.8 MB head slice
        float x = sl_h + srv;
        x = x > 0.f ? x : 0.2f * x;             // LeakyReLU(0.2)
        const float w = (c + cp < cnt) ? __expf(x) : 0.f;
        float ws = w;                            // chunk weight sum (all lanes)
        ws += __shfl_xor(ws, 1); ws += __shfl_xor(ws, 2);
        ws += __shfl_xor(ws, 4); ws += __shfl_xor(ws, 8);
        sum += ws;
        // each lane accumulates 4 edges (eg*4+k) for its channel pair
#pragma unroll
        for (int k = 0; k < 4; k++) {
            const int e = eg * 4 + k;
            const int id = __shfl(idv, e);
            const float wk = __shfl(w, e);
            const int row = (c + e < cnt) ? id : dst;   // clamp dead -> hot line
            const unsigned int u = *reinterpret_cast<const unsigned int*>(
                hb + (((unsigned int)row << 6) + cbyte));
            a0 += wk * __uint_as_float(u << 16);
            a1 += wk * __uint_as_float(u & 0xffff0000u);
        }
    }
    // combine edge groups
    a0 += __shfl_xor(a0, 16); a0 += __shfl_xor(a0, 32);
    a1 += __shfl_xor(a1, 16); a1 += __shfl_xor(a1, 32);
    const float inv = 1.0f / (sum + 1e-16f);
    if (l < 16) { smres[m][cp][0] = a0 * inv; smres[m][cp][1] = a1 * inv; }
    __syncthreads();

    if (m == 0 && l < 16) {
        const unsigned int ud = *reinterpret_cast<const unsigned int*>(
            hb + (((unsigned int)dst << 6) + cbyte));
        const float hd0 = __uint_as_float(ud << 16);
        const float hd1 = __uint_as_float(ud & 0xffff0000u);
        const int ch = hh * kC + cp * 2;        // global channel
        const float bl0 = fmaxf(hd0 * ral[ch], 0.f);
        const float bl1 = fmaxf(hd1 * ral[ch + 1], 0.f);
        float emb0[5], emb1[5], beta[5];
#pragma unroll
        for (int r = 0; r < 5; r++) {
            const float x0 = (r < 4) ? smres[r][cp][0] : hd0;
            const float x1 = (r < 4) ? smres[r][cp][1] : hd1;
            emb0[r] = x0;
            emb1[r] = x1;
            const float br0 = fmaxf(x0 * rar[r * kD + ch], 0.f);
            const float br1 = fmaxf(x1 * rar[r * kD + ch + 1], 0.f);
            float p = bl0 * br0 + bl1 * br1;
            p += __shfl_xor(p, 1);
            p += __shfl_xor(p, 2);
            p += __shfl_xor(p, 4);
            p += __shfl_xor(p, 8);
            beta[r] = p + rbias[r];
        }
        float mx = beta[0];
#pragma unroll
        for (int r = 1; r < 5; r++) mx = fmaxf(mx, beta[r]);
        float s = 0.f, wgt[5];
#pragma unroll
        for (int r = 0; r < 5; r++) { wgt[r] = __expf(beta[r] - mx); s += wgt[r]; }
        const float invb = 1.f / s;
        float o0 = 0.f, o1 = 0.f;
#pragma unroll
        for (int r = 0; r < 5; r++) { o0 += emb0[r] * wgt[r]; o1 += emb1[r] * wgt[r]; }
        __builtin_nontemporal_store(fmaxf(o0 * invb, 0.f), &out[(size_t)dst * kD + ch]);
        __builtin_nontemporal_store(fmaxf(o1 * invb, 0.f), &out[(size_t)dst * kD + ch + 1]);
    }
}

// ---------------------------------------------------------------------------
extern "C" void kernel_launch(void* const* d_in, const int* in_sizes, int n_in,
                              void* d_out, int out_size, void* d_ws, size_t ws_size,
                              hipStream_t stream) {
    const float* feats = (const float*)d_in[0];
    const int* ei      = (const int*)d_in[1];
    const float* W     = (const float*)d_in[2];
    const float* b     = (const float*)d_in[3];
    const float* attn  = (const float*)d_in[4];
    const float* ral   = (const float*)d_in[5];
    const float* rar   = (const float*)d_in[6];
    const float* rbias = (const float*)d_in[7];
    float* out = (float*)d_out;

    char* ws = (char*)d_ws;
    size_t off = 0;
    auto alloc = [&](size_t bytes) -> void* {
        void* p = ws + off;
        off = (off + bytes + 255) & ~(size_t)255;
        return p;
    };
    unsigned short* h16 = (unsigned short*)alloc(sizeof(short) * (size_t)kN * kD); // 12.8 MB
    unsigned short* Wt16= (unsigned short*)alloc(sizeof(short) * (size_t)kD * kIN); // 64 KB
    float* sl   = (float*)alloc(sizeof(float) * (size_t)kM * kN * kH);         // 3.2 MB
    float* sr   = (float*)alloc(sizeof(float) * (size_t)kM * kN * kH);         // 3.2 MB
    int* cnta   = (int*)alloc(sizeof(int) * (size_t)kM * kN);                  // 0.8 MB
    int* offs   = (int*)alloc(sizeof(int) * (size_t)kM * kN);                  // 0.8 MB
    int* bcur   = (int*)alloc(sizeof(int) * (kM * NBK + 64));                  // 392
    unsigned short* srcsort =
        (unsigned short*)alloc(sizeof(short) * ((size_t)kM * MW + 64));        // 8.0 MB
    unsigned int* pairs = (unsigned int*)alloc(sizeof(int) * (size_t)kM * MW); // 16.1 MB

    hipMemsetAsync(bcur, 0, sizeof(int) * (kM * NBK + 64), stream);
    k_wcast<<<kD, kIN, 0, stream>>>(W, Wt16);
    k_gemmbucket<<<GEMMB + kM * PAB, 256, 0, stream>>>(feats, Wt16, b, attn,
                                                       h16, sl, sr, ei, bcur, pairs);
    k_sort<<<SORTB, 256, 0, stream>>>(pairs, bcur, offs, cnta, srcsort);
    k_agg<<<kN * kH, 256, 0, stream>>>(h16, sl, sr, offs, cnta, srcsort,
                                       ral, rar, rbias, out);
}

// Round 10
// 351.103 us; speedup vs baseline: 1.6435x; 1.6435x over previous
//
#include <hip/hip_runtime.h>
#include <math.h>

// Problem constants
#define kN 50000
#define kE 800000
#define kM 4
#define kH 4
#define kC 32
#define kIN 256
#define kD 128   // kH*kC

typedef __attribute__((ext_vector_type(8))) short bf16x8;
typedef __attribute__((ext_vector_type(4))) float f32x4;

__device__ __forceinline__ unsigned int f2bf_pack(float a, float b) {
    unsigned ua = __float_as_uint(a);
    ua += 0x7fffu + ((ua >> 16) & 1u);          // RNE
    unsigned ub = __float_as_uint(b);
    ub += 0x7fffu + ((ub >> 16) & 1u);
    return (ua >> 16) | (ub & 0xffff0000u);
}
__device__ __forceinline__ unsigned short f2bf(float x) {
    unsigned u = __float_as_uint(x);
    u += 0x7fffu + ((u >> 16) & 1u);
    return (unsigned short)(u >> 16);
}

// ---------------------------------------------------------------------------
// Bucket-major CSR: 98 buckets of 512 dsts per metapath, fixed capacity.
#define NBK 98
#define BCAP 10240
#define MW (NBK * BCAP)               // per-m region: 1,003,520 slots
#define PAB ((kE + 4095) / 4096)      // 196 edge chunks per metapath

// ---------------------------------------------------------------------------
// Wt16[col][k] = bf16(W[k][col])  (128 cols x 256 k)
__global__ void k_wcast(const float* __restrict__ W, unsigned short* __restrict__ Wt16) {
    const int col = blockIdx.x;        // 0..127
    const int k = threadIdx.x;         // 0..255
    Wt16[(size_t)col * kIN + k] = f2bf(W[(size_t)k * kD + col]);
}

// ---------------------------------------------------------------------------
// FUSED: blocks [0,GEMMB) = MFMA bf16 GEMM + in-block slr epilogue (node-major
//   h16/sl/sr -- the layouts k_agg's measured-best body wants).
// blocks [GEMMB, GEMMB + kM*PAB) = bucket phase A (independent root).
#define GEMMB ((kN + 127) / 128)          // 391
__global__ __launch_bounds__(256) void k_gemmbucket(const float* __restrict__ feats,
                                                    const unsigned short* __restrict__ Wt16,
                                                    const float* __restrict__ b,
                                                    const float* __restrict__ attn,
                                                    unsigned short* __restrict__ h16,
                                                    float* __restrict__ sl,
                                                    float* __restrict__ sr,
                                                    const int* __restrict__ ei,
                                                    int* __restrict__ bcur,
                                                    unsigned int* __restrict__ pairs) {
    // union: staging fr16 (128x32 u16 = 8192 B) | hlds (64x130 u16 = 16640 B)
    __shared__ __align__(16) unsigned char smem[64 * 130 * 2];
    __shared__ int hist[NBK], h2[NBK], base_s[NBK];
    const int t = threadIdx.x;

    if (blockIdx.x >= GEMMB) {
        // ---- bucket phase A ----
        const int bi = blockIdx.x - GEMMB;
        const int m = bi / PAB;
        const int chunk = bi - m * PAB;
        const int e0 = chunk * 4096;
        for (int j = t; j < NBK; j += 256) { hist[j] = 0; h2[j] = 0; }
        __syncthreads();
        int src[16], dst[16];
#pragma unroll
        for (int i = 0; i < 16; i++) {
            const int e = e0 + i * 256 + t;
            const int eok = (e < kE) ? e : 0;
            src[i] = ei[(size_t)m * 2 * kE + eok];
            dst[i] = (e < kE) ? ei[(size_t)m * 2 * kE + kE + eok] : -1;
        }
#pragma unroll
        for (int i = 0; i < 16; i++)
            if (dst[i] >= 0) atomicAdd(&hist[dst[i] >> 9], 1);
        __syncthreads();
        for (int j = t; j < NBK; j += 256)
            base_s[j] = atomicAdd(&bcur[m * NBK + j], hist[j]);
        __syncthreads();
#pragma unroll
        for (int i = 0; i < 16; i++) {
            if (dst[i] >= 0) {
                const int bk = dst[i] >> 9;
                const int slot = base_s[bk] + atomicAdd(&h2[bk], 1);
                pairs[(size_t)m * MW + (size_t)bk * BCAP + slot] =
                    ((unsigned int)(dst[i] & 511) << 16) | (unsigned int)src[i];
            }
        }
        return;
    }

    // ---- MFMA GEMM ----
    unsigned short* fr16 = reinterpret_cast<unsigned short*>(smem);
    typedef unsigned short hrow_t[130];
    hrow_t* hlds = reinterpret_cast<hrow_t*>(smem);

    const int lane = t & 63;
    const int wave = t >> 6;
    const int q = lane >> 4;           // quad 0..3
    const int m16 = lane & 15;
    const int wrow = (wave >> 1) * 64;
    const int wcol = (wave & 1) * 64;
    const int rowbase = blockIdx.x * 128;

    f32x4 acc[4][4];
#pragma unroll
    for (int i = 0; i < 4; i++)
#pragma unroll
        for (int j = 0; j < 4; j++) acc[i][j] = (f32x4){0.f, 0.f, 0.f, 0.f};

    const int srow = t >> 3;           // staging: 32 rows per pass
    const int sk4 = t & 7;             // float4 slot along k (8 slots = 32 k)

    for (int kc = 0; kc < kIN; kc += 32) {
        __syncthreads();
#pragma unroll
        for (int it = 0; it < 4; it++) {
            const int row = srow + it * 32;
            const int rg = rowbase + row;
            float4 v = make_float4(0.f, 0.f, 0.f, 0.f);
            if (rg < kN)
                v = *reinterpret_cast<const float4*>(feats + (size_t)rg * kIN + kc + sk4 * 4);
            uint2 p;
            p.x = f2bf_pack(v.x, v.y);
            p.y = f2bf_pack(v.z, v.w);
            *reinterpret_cast<uint2*>(&fr16[row * 32 + sk4 * 4]) = p;
        }
        __syncthreads();

        bf16x8 afr[4], bfr[4];
#pragma unroll
        for (int ri = 0; ri < 4; ri++)
            afr[ri] = *reinterpret_cast<const bf16x8*>(
                &fr16[(wrow + ri * 16 + m16) * 32 + q * 8]);
#pragma unroll
        for (int ci = 0; ci < 4; ci++)
            bfr[ci] = *reinterpret_cast<const bf16x8*>(
                Wt16 + (size_t)(wcol + ci * 16 + m16) * kIN + kc + q * 8);
#pragma unroll
        for (int ri = 0; ri < 4; ri++)
#pragma unroll
            for (int ci = 0; ci < 4; ci++)
                acc[ri][ci] = __builtin_amdgcn_mfma_f32_16x16x32_bf16(
                    afr[ri], bfr[ci], acc[ri][ci], 0, 0, 0);
    }

    float bcol[4];
#pragma unroll
    for (int ci = 0; ci < 4; ci++) bcol[ci] = b[wcol + ci * 16 + m16];

    // h16 global write (all 128 rows), node-major
#pragma unroll
    for (int ri = 0; ri < 4; ri++) {
#pragma unroll
        for (int reg = 0; reg < 4; reg++) {
            const int row = wrow + ri * 16 + q * 4 + reg;
            const int rg = rowbase + row;
            if (rg < kN) {
#pragma unroll
                for (int ci = 0; ci < 4; ci++) {
                    const int col = wcol + ci * 16 + m16;
                    const float v = fmaxf(acc[ri][ci][reg] + bcol[ci], 0.f);
                    h16[(size_t)rg * kD + col] = f2bf(v);
                }
            }
        }
    }
    __syncthreads();   // fr16 (last ds_reads) -> hlds aliasing hazard

    // ---- slr epilogue: two 64-row passes over the union'd LDS buffer ----
    const unsigned int* hl32 = reinterpret_cast<const unsigned int*>(smem);
#pragma unroll
    for (int half = 0; half < 2; half++) {
        if ((wrow >> 6) == half) {      // wave-uniform: waves owning these rows
#pragma unroll
            for (int ri = 0; ri < 4; ri++)
#pragma unroll
                for (int reg = 0; reg < 4; reg++) {
                    const int row = (wrow & 63) + ri * 16 + q * 4 + reg;
#pragma unroll
                    for (int ci = 0; ci < 4; ci++) {
                        const int col = wcol + ci * 16 + m16;
                        const float v = fmaxf(acc[ri][ci][reg] + bcol[ci], 0.f);
                        hlds[row][col] = f2bf(v);   // pad rows defined (zero feats)
                    }
                }
        }
        __syncthreads();
        {
            // 256 tasks = 64 rows x 4 heads; hh = t&3, nl = t>>2 ->
            // consecutive lanes write consecutive node-major sl/sr floats.
            const int hh = t & 3;
            const int nl = t >> 2;             // 0..63
            const int n = rowbase + half * 64 + nl;
            if (n < kN) {
                unsigned int u[16];
#pragma unroll
                for (int k = 0; k < 16; k++) u[k] = hl32[nl * 65 + hh * 16 + k];
                float f0[16], f1[16];
#pragma unroll
                for (int k = 0; k < 16; k++) {
                    f0[k] = __uint_as_float(u[k] << 16);
                    f1[k] = __uint_as_float(u[k] & 0xffff0000u);
                }
#pragma unroll
                for (int m = 0; m < kM; m++) {
                    const float2* al = reinterpret_cast<const float2*>(attn + (m * kH + hh) * 2 * kC);
                    const float2* ar = al + 16;
                    float s0 = 0.f, s1 = 0.f;
#pragma unroll
                    for (int k = 0; k < 16; k++) {
                        const float2 a = al[k], r = ar[k];
                        s0 += f0[k] * a.x + f1[k] * a.y;
                        s1 += f0[k] * r.x + f1[k] * r.y;
                    }
                    sl[((size_t)m * kN + n) * kH + hh] = s0;   // node-major
                    sr[((size_t)m * kN + n) * kH + hh] = s1;
                }
            }
        }
        __syncthreads();
    }
}

// ---------------------------------------------------------------------------
// Per-(m,bucket) LOCAL count+scan+place, single pass over pairs; u16 srcsort;
// per-block slack zeroing (no global memset).
#define SORTB (kM * NBK)                       // 392
__global__ __launch_bounds__(256) void k_sort(const unsigned int* __restrict__ pairs,
                                              const int* __restrict__ bcur,
                                              int* __restrict__ offs,
                                              int* __restrict__ cnta,
                                              unsigned short* __restrict__ srcsort) {
    __shared__ int hist[512], pref[512], h2[512], wt[4];
    const int t = threadIdx.x;
    const int m = blockIdx.x / NBK;
    const int bk = blockIdx.x - m * NBK;
    const int bs = bk << 9;
    const int base = bk * BCAP;
    const int n = bcur[m * NBK + bk];          // exact bucket fill from phase A
    const unsigned int* __restrict__ pb = pairs + (size_t)m * MW + base;
    unsigned short* __restrict__ ss = srcsort + (size_t)m * MW + base;

    hist[t] = 0; hist[t + 256] = 0; h2[t] = 0; h2[t + 256] = 0;
    __syncthreads();

    unsigned int v[40];
#pragma unroll
    for (int j = 0; j < 40; j++) {
        const int idx = j * 256 + t;
        v[j] = (idx < n) ? pb[idx] : 0xffffffffu;   // valid pairs < 0x02000000
    }
#pragma unroll
    for (int j = 0; j < 40; j++)
        if (v[j] != 0xffffffffu) atomicAdd(&hist[v[j] >> 16], 1);
    __syncthreads();

    const int lane = t & 63, wid = t >> 6;
    const int j0 = 2 * t, j1 = 2 * t + 1;
    const int h0 = hist[j0], h1 = hist[j1];
    const int s = h0 + h1;
    int incl = s;
#pragma unroll
    for (int d = 1; d < 64; d <<= 1) {
        const int x = __shfl_up(incl, d);
        if (lane >= d) incl += x;
    }
    if (lane == 63) wt[wid] = incl;
    __syncthreads();
    int woff = 0;
#pragma unroll
    for (int i = 0; i < 4; i++)
        if (i < wid) woff += wt[i];
    const int excl = woff + incl - s;
    pref[j0] = excl;
    pref[j1] = excl + h0;
    const int d0 = bs + j0, d1 = bs + j1;
    if (d0 < kN) { offs[m * kN + d0] = base + excl;       cnta[m * kN + d0] = h0; }
    if (d1 < kN) { offs[m * kN + d1] = base + excl + h0;  cnta[m * kN + d1] = h1; }
    __syncthreads();

#pragma unroll
    for (int j = 0; j < 40; j++) {
        if (v[j] != 0xffffffffu) {
            const int dl = (int)(v[j] >> 16);
            const int pos = pref[dl] + atomicAdd(&h2[dl], 1);
            ss[pos] = (unsigned short)(v[j] & 0xffffu);
        }
    }
    // zero the over-read slack (reads never exceed n+48; stay inside window)
    if (t < 64 && n + t < BCAP) ss[n + t] = 0;
}

// ---------------------------------------------------------------------------
// aggregation R16 = R14's measured-best body (153.8 us / 530 MB) + nontemporal
// hints on single-use streams (srcsort ids, offs/cnta/sl scalars, out stores)
// so they stop competing with the hot h16 (12.8 MB) / sr (3.2 MB) tables in
// L2. R15 post-mortem: head-slicing cut FETCH 530->72 MB but bpermute chains
// + 4x block overhead made it 417 us -- the useful per-(edge,head) VALU work
// is layout-invariant, so the R14 body stays.
#define CH 16

#define AGG_BODY(GN)                                                            \
    {                                                                           \
        int sj[GN];                                                             \
        _Pragma("unroll")                                                       \
        for (int j = 0; j < GN; j++) {                                          \
            const int id = __builtin_amdgcn_readlane(my0, j);                   \
            sj[j] = (j < nb) ? id : dst;                                        \
        }                                                                       \
        unsigned int u[GN];                                                     \
        _Pragma("unroll")                                                       \
        for (int j = 0; j < GN; j++)                                            \
            u[j] = *reinterpret_cast<const unsigned int*>(                      \
                hb + (((size_t)(unsigned int)sj[j] << 8) + ebyte));             \
        float x = sl_h + srv;                                                   \
        x = x > 0.f ? x : 0.2f * x;            /* LeakyReLU(0.2) */             \
        const float w = (c + jj < cnt) ? __expf(x) : 0.f;                       \
        sum += w;                                                               \
        swts[m][l] = w;                                                         \
        __builtin_amdgcn_wave_barrier();                                        \
        const float4 w0 = *reinterpret_cast<const float4*>(&swts[m][hh * 16]);  \
        const float4 w1 = *reinterpret_cast<const float4*>(&swts[m][hh*16+4]);  \
        const float4 w2 = *reinterpret_cast<const float4*>(&swts[m][hh*16+8]);  \
        const float4 w3 = *reinterpret_cast<const float4*>(&swts[m][hh*16+12]); \
        __builtin_amdgcn_wave_barrier();                                        \
        my0 = my1;                                                              \
        my1 = (int)__builtin_nontemporal_load(&sbase[c + 2 * CH + jj]);         \
        srv = *reinterpret_cast<const float*>(                                  \
            srb + (((unsigned int)my0 << 4) + hbyte));                          \
        const float wj[16] = {w0.x, w0.y, w0.z, w0.w, w1.x, w1.y, w1.z, w1.w,   \
                              w2.x, w2.y, w2.z, w2.w, w3.x, w3.y, w3.z, w3.w};  \
        _Pragma("unroll")                                                       \
        for (int j = 0; j < GN; j++) {                                          \
            a0 += wj[j] * __uint_as_float(u[j] << 16);                          \
            a1 += wj[j] * __uint_as_float(u[j] & 0xffff0000u);                  \
        }                                                                       \
    }

__global__ __launch_bounds__(256) void k_agg(const unsigned short* __restrict__ h16,
                                             const float* __restrict__ sl,
                                             const float* __restrict__ sr,
                                             const int* __restrict__ offs,
                                             const int* __restrict__ cnta,
                                             const unsigned short* __restrict__ srcsort,
                                             const float* __restrict__ ral,
                                             const float* __restrict__ rar,
                                             const float* __restrict__ rbias,
                                             float* __restrict__ out) {
    const int dst = blockIdx.x;
    const int t = threadIdx.x;
    const int m = t >> 6;
    const int l = t & 63;
    const int hh = l >> 4;        // head for this lane
    const int jj = l & 15;        // edge slot this lane computes the weight for
    const int e0 = l * 2;         // channel pair e0, e0+1

    __shared__ float smres[kM][kD];
    __shared__ float swts[kM][64];

    const int beg = __builtin_nontemporal_load(&offs[m * kN + dst]);
    const int cnt = __builtin_nontemporal_load(&cnta[m * kN + dst]);
    const float sl_h = __builtin_nontemporal_load(&sl[((size_t)m * kN + dst) * kH + hh]);
    const unsigned short* __restrict__ sbase = srcsort + (size_t)m * MW + beg;
    const char* __restrict__ hb = (const char*)h16;
    const char* __restrict__ srb = (const char*)(sr + (size_t)m * kN * kH);
    const unsigned int ebyte = (unsigned int)(e0 << 1);
    const unsigned int hbyte = (unsigned int)(hh << 2);

    float sum = 0.f, a0 = 0.f, a1 = 0.f;

    // prologue prefetch (over-read safe: same-bucket successors are valid
    // ids; slack is zeroed -> row 0; dead slots get weight 0 + clamp)
    int my0 = (int)__builtin_nontemporal_load(&sbase[jj]);
    int my1 = (int)__builtin_nontemporal_load(&sbase[CH + jj]);
    float srv = *reinterpret_cast<const float*>(
        srb + (((unsigned int)my0 << 4) + hbyte));

    for (int c = 0; c < cnt; c += CH) {
        const int nb = cnt - c;   // wave-uniform chunk occupancy
        if (nb >= 9) AGG_BODY(16) else AGG_BODY(8)
    }

    sum += __shfl_xor(sum, 1);
    sum += __shfl_xor(sum, 2);
    sum += __shfl_xor(sum, 4);
    sum += __shfl_xor(sum, 8);
    const float inv = 1.0f / (sum + 1e-16f);
    smres[m][e0] = a0 * inv;
    smres[m][e0 + 1] = a1 * inv;
    __syncthreads();

    if (m == 0) {
        const unsigned int ud = *reinterpret_cast<const unsigned int*>(
            hb + (((unsigned int)dst << 8) + ebyte));
        const float hd0 = __uint_as_float(ud << 16);
        const float hd1 = __uint_as_float(ud & 0xffff0000u);
        const float bl0 = fmaxf(hd0 * ral[e0], 0.f);
        const float bl1 = fmaxf(hd1 * ral[e0 + 1], 0.f);
        float emb0[5], emb1[5], beta[5];
#pragma unroll
        for (int r = 0; r < 5; r++) {
            const float x0 = (r < 4) ? smres[r][e0] : hd0;
            const float x1 = (r < 4) ? smres[r][e0 + 1] : hd1;
            emb0[r] = x0;
            emb1[r] = x1;
            const float br0 = fmaxf(x0 * rar[r * kD + e0], 0.f);
            const float br1 = fmaxf(x1 * rar[r * kD + e0 + 1], 0.f);
            float p = bl0 * br0 + bl1 * br1;
            p += __shfl_xor(p, 1);
            p += __shfl_xor(p, 2);
            p += __shfl_xor(p, 4);
            p += __shfl_xor(p, 8);
            beta[r] = p + rbias[r];
        }
        float mx = beta[0];
#pragma unroll
        for (int r = 1; r < 5; r++) mx = fmaxf(mx, beta[r]);
        float s = 0.f, wgt[5];
#pragma unroll
        for (int r = 0; r < 5; r++) { wgt[r] = __expf(beta[r] - mx); s += wgt[r]; }
        const float invb = 1.f / s;
        float o0 = 0.f, o1 = 0.f;
#pragma unroll
        for (int r = 0; r < 5; r++) { o0 += emb0[r] * wgt[r]; o1 += emb1[r] * wgt[r]; }
        __builtin_nontemporal_store(fmaxf(o0 * invb, 0.f), &out[(size_t)dst * kD + e0]);
        __builtin_nontemporal_store(fmaxf(o1 * invb, 0.f), &out[(size_t)dst * kD + e0 + 1]);
    }
}

// ---------------------------------------------------------------------------
extern "C" void kernel_launch(void* const* d_in, const int* in_sizes, int n_in,
                              void* d_out, int out_size, void* d_ws, size_t ws_size,
                              hipStream_t stream) {
    const float* feats = (const float*)d_in[0];
    const int* ei      = (const int*)d_in[1];
    const float* W     = (const float*)d_in[2];
    const float* b     = (const float*)d_in[3];
    const float* attn  = (const float*)d_in[4];
    const float* ral   = (const float*)d_in[5];
    const float* rar   = (const float*)d_in[6];
    const float* rbias = (const float*)d_in[7];
    float* out = (float*)d_out;

    char* ws = (char*)d_ws;
    size_t off = 0;
    auto alloc = [&](size_t bytes) -> void* {
        void* p = ws + off;
        off = (off + bytes + 255) & ~(size_t)255;
        return p;
    };
    unsigned short* h16 = (unsigned short*)alloc(sizeof(short) * (size_t)kN * kD); // 12.8 MB
    unsigned short* Wt16= (unsigned short*)alloc(sizeof(short) * (size_t)kD * kIN); // 64 KB
    float* sl   = (float*)alloc(sizeof(float) * (size_t)kM * kN * kH);         // 3.2 MB
    float* sr   = (float*)alloc(sizeof(float) * (size_t)kM * kN * kH);         // 3.2 MB
    int* cnta   = (int*)alloc(sizeof(int) * (size_t)kM * kN);                  // 0.8 MB
    int* offs   = (int*)alloc(sizeof(int) * (size_t)kM * kN);                  // 0.8 MB
    int* bcur   = (int*)alloc(sizeof(int) * (kM * NBK + 64));                  // 392
    unsigned short* srcsort =
        (unsigned short*)alloc(sizeof(short) * ((size_t)kM * MW + 64));        // 8.0 MB
    unsigned int* pairs = (unsigned int*)alloc(sizeof(int) * (size_t)kM * MW); // 16.1 MB

    hipMemsetAsync(bcur, 0, sizeof(int) * (kM * NBK + 64), stream);
    k_wcast<<<kD, kIN, 0, stream>>>(W, Wt16);
    k_gemmbucket<<<GEMMB + kM * PAB, 256, 0, stream>>>(feats, Wt16, b, attn,
                                                       h16, sl, sr, ei, bcur, pairs);
    k_sort<<<SORTB, 256, 0, stream>>>(pairs, bcur, offs, cnta, srcsort);
    k_agg<<<kN, 256, 0, stream>>>(h16, sl, sr, offs, cnta, srcsort,
                                  ral, rar, rbias, out);
}

// Round 11
// 340.674 us; speedup vs baseline: 1.6939x; 1.0306x over previous
//
#include <hip/hip_runtime.h>
#include <math.h>

// Problem constants
#define kN 50000
#define kE 800000
#define kM 4
#define kH 4
#define kC 32
#define kIN 256
#define kD 128   // kH*kC

typedef __attribute__((ext_vector_type(8))) short bf16x8;
typedef __attribute__((ext_vector_type(4))) float f32x4;

__device__ __forceinline__ unsigned int f2bf_pack(float a, float b) {
    unsigned ua = __float_as_uint(a);
    ua += 0x7fffu + ((ua >> 16) & 1u);          // RNE
    unsigned ub = __float_as_uint(b);
    ub += 0x7fffu + ((ub >> 16) & 1u);
    return (ua >> 16) | (ub & 0xffff0000u);
}
__device__ __forceinline__ unsigned short f2bf(float x) {
    unsigned u = __float_as_uint(x);
    u += 0x7fffu + ((u >> 16) & 1u);
    return (unsigned short)(u >> 16);
}

// ---------------------------------------------------------------------------
// Bucket-major CSR: 98 buckets of 512 dsts per metapath, fixed capacity.
#define NBK 98
#define BCAP 10240
#define MW (NBK * BCAP)               // per-m region: 1,003,520 slots
#define PAB ((kE + 4095) / 4096)      // 196 edge chunks per metapath

// ---------------------------------------------------------------------------
// Wt16[col][k] = bf16(W[k][col])  (128 cols x 256 k)
__global__ void k_wcast(const float* __restrict__ W, unsigned short* __restrict__ Wt16) {
    const int col = blockIdx.x;        // 0..127
    const int k = threadIdx.x;         // 0..255
    Wt16[(size_t)col * kIN + k] = f2bf(W[(size_t)k * kD + col]);
}

// ---------------------------------------------------------------------------
// FUSED: blocks [0,GEMMB) = MFMA bf16 GEMM + in-block slr epilogue (node-major
//   h16/sl/sr -- the layouts k_agg's measured-best body wants).
// blocks [GEMMB, GEMMB + kM*PAB) = bucket phase A (independent root).
#define GEMMB ((kN + 127) / 128)          // 391
__global__ __launch_bounds__(256) void k_gemmbucket(const float* __restrict__ feats,
                                                    const unsigned short* __restrict__ Wt16,
                                                    const float* __restrict__ b,
                                                    const float* __restrict__ attn,
                                                    unsigned short* __restrict__ h16,
                                                    float* __restrict__ sl,
                                                    float* __restrict__ sr,
                                                    const int* __restrict__ ei,
                                                    int* __restrict__ bcur,
                                                    unsigned int* __restrict__ pairs) {
    // union: staging fr16 (128x32 u16 = 8192 B) | hlds (64x130 u16 = 16640 B)
    __shared__ __align__(16) unsigned char smem[64 * 130 * 2];
    __shared__ int hist[NBK], h2[NBK], base_s[NBK];
    const int t = threadIdx.x;

    if (blockIdx.x >= GEMMB) {
        // ---- bucket phase A ----
        const int bi = blockIdx.x - GEMMB;
        const int m = bi / PAB;
        const int chunk = bi - m * PAB;
        const int e0 = chunk * 4096;
        for (int j = t; j < NBK; j += 256) { hist[j] = 0; h2[j] = 0; }
        __syncthreads();
        int src[16], dst[16];
#pragma unroll
        for (int i = 0; i < 16; i++) {
            const int e = e0 + i * 256 + t;
            const int eok = (e < kE) ? e : 0;
            src[i] = ei[(size_t)m * 2 * kE + eok];
            dst[i] = (e < kE) ? ei[(size_t)m * 2 * kE + kE + eok] : -1;
        }
#pragma unroll
        for (int i = 0; i < 16; i++)
            if (dst[i] >= 0) atomicAdd(&hist[dst[i] >> 9], 1);
        __syncthreads();
        for (int j = t; j < NBK; j += 256)
            base_s[j] = atomicAdd(&bcur[m * NBK + j], hist[j]);
        __syncthreads();
#pragma unroll
        for (int i = 0; i < 16; i++) {
            if (dst[i] >= 0) {
                const int bk = dst[i] >> 9;
                const int slot = base_s[bk] + atomicAdd(&h2[bk], 1);
                pairs[(size_t)m * MW + (size_t)bk * BCAP + slot] =
                    ((unsigned int)(dst[i] & 511) << 16) | (unsigned int)src[i];
            }
        }
        return;
    }

    // ---- MFMA GEMM ----
    unsigned short* fr16 = reinterpret_cast<unsigned short*>(smem);
    typedef unsigned short hrow_t[130];
    hrow_t* hlds = reinterpret_cast<hrow_t*>(smem);

    const int lane = t & 63;
    const int wave = t >> 6;
    const int q = lane >> 4;           // quad 0..3
    const int m16 = lane & 15;
    const int wrow = (wave >> 1) * 64;
    const int wcol = (wave & 1) * 64;
    const int rowbase = blockIdx.x * 128;

    f32x4 acc[4][4];
#pragma unroll
    for (int i = 0; i < 4; i++)
#pragma unroll
        for (int j = 0; j < 4; j++) acc[i][j] = (f32x4){0.f, 0.f, 0.f, 0.f};

    const int srow = t >> 3;           // staging: 32 rows per pass
    const int sk4 = t & 7;             // float4 slot along k (8 slots = 32 k)

    for (int kc = 0; kc < kIN; kc += 32) {
        __syncthreads();
#pragma unroll
        for (int it = 0; it < 4; it++) {
            const int row = srow + it * 32;
            const int rg = rowbase + row;
            float4 v = make_float4(0.f, 0.f, 0.f, 0.f);
            if (rg < kN)
                v = *reinterpret_cast<const float4*>(feats + (size_t)rg * kIN + kc + sk4 * 4);
            uint2 p;
            p.x = f2bf_pack(v.x, v.y);
            p.y = f2bf_pack(v.z, v.w);
            *reinterpret_cast<uint2*>(&fr16[row * 32 + sk4 * 4]) = p;
        }
        __syncthreads();

        bf16x8 afr[4], bfr[4];
#pragma unroll
        for (int ri = 0; ri < 4; ri++)
            afr[ri] = *reinterpret_cast<const bf16x8*>(
                &fr16[(wrow + ri * 16 + m16) * 32 + q * 8]);
#pragma unroll
        for (int ci = 0; ci < 4; ci++)
            bfr[ci] = *reinterpret_cast<const bf16x8*>(
                Wt16 + (size_t)(wcol + ci * 16 + m16) * kIN + kc + q * 8);
#pragma unroll
        for (int ri = 0; ri < 4; ri++)
#pragma unroll
            for (int ci = 0; ci < 4; ci++)
                acc[ri][ci] = __builtin_amdgcn_mfma_f32_16x16x32_bf16(
                    afr[ri], bfr[ci], acc[ri][ci], 0, 0, 0);
    }

    float bcol[4];
#pragma unroll
    for (int ci = 0; ci < 4; ci++) bcol[ci] = b[wcol + ci * 16 + m16];

    // h16 global write (all 128 rows), node-major
#pragma unroll
    for (int ri = 0; ri < 4; ri++) {
#pragma unroll
        for (int reg = 0; reg < 4; reg++) {
            const int row = wrow + ri * 16 + q * 4 + reg;
            const int rg = rowbase + row;
            if (rg < kN) {
#pragma unroll
                for (int ci = 0; ci < 4; ci++) {
                    const int col = wcol + ci * 16 + m16;
                    const float v = fmaxf(acc[ri][ci][reg] + bcol[ci], 0.f);
                    h16[(size_t)rg * kD + col] = f2bf(v);
                }
            }
        }
    }
    __syncthreads();   // fr16 (last ds_reads) -> hlds aliasing hazard

    // ---- slr epilogue: two 64-row passes over the union'd LDS buffer ----
    const unsigned int* hl32 = reinterpret_cast<const unsigned int*>(smem);
#pragma unroll
    for (int half = 0; half < 2; half++) {
        if ((wrow >> 6) == half) {      // wave-uniform: waves owning these rows
#pragma unroll
            for (int ri = 0; ri < 4; ri++)
#pragma unroll
                for (int reg = 0; reg < 4; reg++) {
                    const int row = (wrow & 63) + ri * 16 + q * 4 + reg;
#pragma unroll
                    for (int ci = 0; ci < 4; ci++) {
                        const int col = wcol + ci * 16 + m16;
                        const float v = fmaxf(acc[ri][ci][reg] + bcol[ci], 0.f);
                        hlds[row][col] = f2bf(v);   // pad rows defined (zero feats)
                    }
                }
        }
        __syncthreads();
        {
            // 256 tasks = 64 rows x 4 heads; hh = t&3, nl = t>>2 ->
            // consecutive lanes write consecutive node-major sl/sr floats.
            const int hh = t & 3;
            const int nl = t >> 2;             // 0..63
            const int n = rowbase + half * 64 + nl;
            if (n < kN) {
                unsigned int u[16];
#pragma unroll
                for (int k = 0; k < 16; k++) u[k] = hl32[nl * 65 + hh * 16 + k];
                float f0[16], f1[16];
#pragma unroll
                for (int k = 0; k < 16; k++) {
                    f0[k] = __uint_as_float(u[k] << 16);
                    f1[k] = __uint_as_float(u[k] & 0xffff0000u);
                }
#pragma unroll
                for (int m = 0; m < kM; m++) {
                    const float2* al = reinterpret_cast<const float2*>(attn + (m * kH + hh) * 2 * kC);
                    const float2* ar = al + 16;
                    float s0 = 0.f, s1 = 0.f;
#pragma unroll
                    for (int k = 0; k < 16; k++) {
                        const float2 a = al[k], r = ar[k];
                        s0 += f0[k] * a.x + f1[k] * a.y;
                        s1 += f0[k] * r.x + f1[k] * r.y;
                    }
                    sl[((size_t)m * kN + n) * kH + hh] = s0;   // node-major
                    sr[((size_t)m * kN + n) * kH + hh] = s1;
                }
            }
        }
        __syncthreads();
    }
}

// ---------------------------------------------------------------------------
// Per-(m,bucket) LOCAL count+scan+place, single pass over pairs; u16 srcsort;
// per-block slack zeroing (no global memset).
#define SORTB (kM * NBK)                       // 392
__global__ __launch_bounds__(256) void k_sort(const unsigned int* __restrict__ pairs,
                                              const int* __restrict__ bcur,
                                              int* __restrict__ offs,
                                              int* __restrict__ cnta,
                                              unsigned short* __restrict__ srcsort) {
    __shared__ int hist[512], pref[512], h2[512], wt[4];
    const int t = threadIdx.x;
    const int m = blockIdx.x / NBK;
    const int bk = blockIdx.x - m * NBK;
    const int bs = bk << 9;
    const int base = bk * BCAP;
    const int n = bcur[m * NBK + bk];          // exact bucket fill from phase A
    const unsigned int* __restrict__ pb = pairs + (size_t)m * MW + base;
    unsigned short* __restrict__ ss = srcsort + (size_t)m * MW + base;

    hist[t] = 0; hist[t + 256] = 0; h2[t] = 0; h2[t + 256] = 0;
    __syncthreads();

    unsigned int v[40];
#pragma unroll
    for (int j = 0; j < 40; j++) {
        const int idx = j * 256 + t;
        v[j] = (idx < n) ? pb[idx] : 0xffffffffu;   // valid pairs < 0x02000000
    }
#pragma unroll
    for (int j = 0; j < 40; j++)
        if (v[j] != 0xffffffffu) atomicAdd(&hist[v[j] >> 16], 1);
    __syncthreads();

    const int lane = t & 63, wid = t >> 6;
    const int j0 = 2 * t, j1 = 2 * t + 1;
    const int h0 = hist[j0], h1 = hist[j1];
    const int s = h0 + h1;
    int incl = s;
#pragma unroll
    for (int d = 1; d < 64; d <<= 1) {
        const int x = __shfl_up(incl, d);
        if (lane >= d) incl += x;
    }
    if (lane == 63) wt[wid] = incl;
    __syncthreads();
    int woff = 0;
#pragma unroll
    for (int i = 0; i < 4; i++)
        if (i < wid) woff += wt[i];
    const int excl = woff + incl - s;
    pref[j0] = excl;
    pref[j1] = excl + h0;
    const int d0 = bs + j0, d1 = bs + j1;
    if (d0 < kN) { offs[m * kN + d0] = base + excl;       cnta[m * kN + d0] = h0; }
    if (d1 < kN) { offs[m * kN + d1] = base + excl + h0;  cnta[m * kN + d1] = h1; }
    __syncthreads();

#pragma unroll
    for (int j = 0; j < 40; j++) {
        if (v[j] != 0xffffffffu) {
            const int dl = (int)(v[j] >> 16);
            const int pos = pref[dl] + atomicAdd(&h2[dl], 1);
            ss[pos] = (unsigned short)(v[j] & 0xffffu);
        }
    }
    // zero the over-read slack (reads never exceed n+48; stay inside window)
    if (t < 64 && n + t < BCAP) ss[n + t] = 0;
}

// ---------------------------------------------------------------------------
// aggregation R17 = byte-exact R14 body (measured 153.8 us / 530 MB / 71% occ,
// reproduced 3x). Reverted experiments, both with counter evidence:
//  - R15 head-slicing: FETCH 530->72 MB but 417 us (bpermute chains + 4x
//    block overhead) -- layout-invariant VALU work means no net win.
//  - R16 NT hints: srcsort lines ARE reused (64B line = 2 chunks), NT
//    evict-first broke that -> 165 us at same FETCH. No NT anywhere here.
#define CH 16

#define AGG_BODY(GN)                                                            \
    {                                                                           \
        int sj[GN];                                                             \
        _Pragma("unroll")                                                       \
        for (int j = 0; j < GN; j++) {                                          \
            const int id = __builtin_amdgcn_readlane(my0, j);                   \
            sj[j] = (j < nb) ? id : dst;                                        \
        }                                                                       \
        unsigned int u[GN];                                                     \
        _Pragma("unroll")                                                       \
        for (int j = 0; j < GN; j++)                                            \
            u[j] = *reinterpret_cast<const unsigned int*>(                      \
                hb + (((size_t)(unsigned int)sj[j] << 8) + ebyte));             \
        float x = sl_h + srv;                                                   \
        x = x > 0.f ? x : 0.2f * x;            /* LeakyReLU(0.2) */             \
        const float w = (c + jj < cnt) ? __expf(x) : 0.f;                       \
        sum += w;                                                               \
        swts[m][l] = w;                                                         \
        __builtin_amdgcn_wave_barrier();                                        \
        const float4 w0 = *reinterpret_cast<const float4*>(&swts[m][hh * 16]);  \
        const float4 w1 = *reinterpret_cast<const float4*>(&swts[m][hh*16+4]);  \
        const float4 w2 = *reinterpret_cast<const float4*>(&swts[m][hh*16+8]);  \
        const float4 w3 = *reinterpret_cast<const float4*>(&swts[m][hh*16+12]); \
        __builtin_amdgcn_wave_barrier();                                        \
        my0 = my1;                                                              \
        my1 = sbase[c + 2 * CH + jj];                                           \
        srv = *reinterpret_cast<const float*>(                                  \
            srb + (((unsigned int)my0 << 4) + hbyte));                          \
        const float wj[16] = {w0.x, w0.y, w0.z, w0.w, w1.x, w1.y, w1.z, w1.w,   \
                              w2.x, w2.y, w2.z, w2.w, w3.x, w3.y, w3.z, w3.w};  \
        _Pragma("unroll")                                                       \
        for (int j = 0; j < GN; j++) {                                          \
            a0 += wj[j] * __uint_as_float(u[j] << 16);                          \
            a1 += wj[j] * __uint_as_float(u[j] & 0xffff0000u);                  \
        }                                                                       \
    }

__global__ __launch_bounds__(256) void k_agg(const unsigned short* __restrict__ h16,
                                             const float* __restrict__ sl,
                                             const float* __restrict__ sr,
                                             const int* __restrict__ offs,
                                             const int* __restrict__ cnta,
                                             const unsigned short* __restrict__ srcsort,
                                             const float* __restrict__ ral,
                                             const float* __restrict__ rar,
                                             const float* __restrict__ rbias,
                                             float* __restrict__ out) {
    const int dst = blockIdx.x;
    const int t = threadIdx.x;
    const int m = t >> 6;
    const int l = t & 63;
    const int hh = l >> 4;        // head for this lane
    const int jj = l & 15;        // edge slot this lane computes the weight for
    const int e0 = l * 2;         // channel pair e0, e0+1

    __shared__ float smres[kM][kD];
    __shared__ float swts[kM][64];

    const int beg = offs[m * kN + dst];
    const int cnt = cnta[m * kN + dst];
    const float sl_h = sl[((size_t)m * kN + dst) * kH + hh];
    const unsigned short* __restrict__ sbase = srcsort + (size_t)m * MW + beg;
    const char* __restrict__ hb = (const char*)h16;
    const char* __restrict__ srb = (const char*)(sr + (size_t)m * kN * kH);
    const unsigned int ebyte = (unsigned int)(e0 << 1);
    const unsigned int hbyte = (unsigned int)(hh << 2);

    float sum = 0.f, a0 = 0.f, a1 = 0.f;

    // prologue prefetch (over-read safe: same-bucket successors are valid
    // ids; slack is zeroed -> row 0; dead slots get weight 0 + clamp)
    int my0 = sbase[jj];
    int my1 = sbase[CH + jj];
    float srv = *reinterpret_cast<const float*>(
        srb + (((unsigned int)my0 << 4) + hbyte));

    for (int c = 0; c < cnt; c += CH) {
        const int nb = cnt - c;   // wave-uniform chunk occupancy
        if (nb >= 9) AGG_BODY(16) else AGG_BODY(8)
    }

    sum += __shfl_xor(sum, 1);
    sum += __shfl_xor(sum, 2);
    sum += __shfl_xor(sum, 4);
    sum += __shfl_xor(sum, 8);
    const float inv = 1.0f / (sum + 1e-16f);
    smres[m][e0] = a0 * inv;
    smres[m][e0 + 1] = a1 * inv;
    __syncthreads();

    if (m == 0) {
        const unsigned int ud = *reinterpret_cast<const unsigned int*>(
            hb + (((unsigned int)dst << 8) + ebyte));
        const float hd0 = __uint_as_float(ud << 16);
        const float hd1 = __uint_as_float(ud & 0xffff0000u);
        const float bl0 = fmaxf(hd0 * ral[e0], 0.f);
        const float bl1 = fmaxf(hd1 * ral[e0 + 1], 0.f);
        float emb0[5], emb1[5], beta[5];
#pragma unroll
        for (int r = 0; r < 5; r++) {
            const float x0 = (r < 4) ? smres[r][e0] : hd0;
            const float x1 = (r < 4) ? smres[r][e0 + 1] : hd1;
            emb0[r] = x0;
            emb1[r] = x1;
            const float br0 = fmaxf(x0 * rar[r * kD + e0], 0.f);
            const float br1 = fmaxf(x1 * rar[r * kD + e0 + 1], 0.f);
            float p = bl0 * br0 + bl1 * br1;
            p += __shfl_xor(p, 1);
            p += __shfl_xor(p, 2);
            p += __shfl_xor(p, 4);
            p += __shfl_xor(p, 8);
            beta[r] = p + rbias[r];
        }
        float mx = beta[0];
#pragma unroll
        for (int r = 1; r < 5; r++) mx = fmaxf(mx, beta[r]);
        float s = 0.f, wgt[5];
#pragma unroll
        for (int r = 0; r < 5; r++) { wgt[r] = __expf(beta[r] - mx); s += wgt[r]; }
        const float invb = 1.f / s;
        float o0 = 0.f, o1 = 0.f;
#pragma unroll
        for (int r = 0; r < 5; r++) { o0 += emb0[r] * wgt[r]; o1 += emb1[r] * wgt[r]; }
        out[(size_t)dst * kD + e0] = fmaxf(o0 * invb, 0.f);
        out[(size_t)dst * kD + e0 + 1] = fmaxf(o1 * invb, 0.f);
    }
}

// ---------------------------------------------------------------------------
extern "C" void kernel_launch(void* const* d_in, const int* in_sizes, int n_in,
                              void* d_out, int out_size, void* d_ws, size_t ws_size,
                              hipStream_t stream) {
    const float* feats = (const float*)d_in[0];
    const int* ei      = (const int*)d_in[1];
    const float* W     = (const float*)d_in[2];
    const float* b     = (const float*)d_in[3];
    const float* attn  = (const float*)d_in[4];
    const float* ral   = (const float*)d_in[5];
    const float* rar   = (const float*)d_in[6];
    const float* rbias = (const float*)d_in[7];
    float* out = (float*)d_out;

    char* ws = (char*)d_ws;
    size_t off = 0;
    auto alloc = [&](size_t bytes) -> void* {
        void* p = ws + off;
        off = (off + bytes + 255) & ~(size_t)255;
        return p;
    };
    unsigned short* h16 = (unsigned short*)alloc(sizeof(short) * (size_t)kN * kD); // 12.8 MB
    unsigned short* Wt16= (unsigned short*)alloc(sizeof(short) * (size_t)kD * kIN); // 64 KB
    float* sl   = (float*)alloc(sizeof(float) * (size_t)kM * kN * kH);         // 3.2 MB
    float* sr   = (float*)alloc(sizeof(float) * (size_t)kM * kN * kH);         // 3.2 MB
    int* cnta   = (int*)alloc(sizeof(int) * (size_t)kM * kN);                  // 0.8 MB
    int* offs   = (int*)alloc(sizeof(int) * (size_t)kM * kN);                  // 0.8 MB
    int* bcur   = (int*)alloc(sizeof(int) * (kM * NBK + 64));                  // 392
    unsigned short* srcsort =
        (unsigned short*)alloc(sizeof(short) * ((size_t)kM * MW + 64));        // 8.0 MB
    unsigned int* pairs = (unsigned int*)alloc(sizeof(int) * (size_t)kM * MW); // 16.1 MB

    hipMemsetAsync(bcur, 0, sizeof(int) * (kM * NBK + 64), stream);
    k_wcast<<<kD, kIN, 0, stream>>>(W, Wt16);
    k_gemmbucket<<<GEMMB + kM * PAB, 256, 0, stream>>>(feats, Wt16, b, attn,
                                                       h16, sl, sr, ei, bcur, pairs);
    k_sort<<<SORTB, 256, 0, stream>>>(pairs, bcur, offs, cnta, srcsort);
    k_agg<<<kN, 256, 0, stream>>>(h16, sl, sr, offs, cnta, srcsort,
                                  ral, rar, rbias, out);
}